// Round 15
// baseline (39.071 us; speedup 1.0000x reference)
//
#include <hip/hip_runtime.h>
#include <math.h>

#define NUM_CLASSES 80
#define M_GT 128
#define ABLK 256     // anchors per block; 512 threads = 2 GT-halves per anchor
#define GRP  32      // blocks per done-group

__device__ __forceinline__ float focal_neg(float x) {
    // (1-ALPHA)=0.75, t=0 term: 0.75 * p^2 * (max(x,0)+log1p(exp(-|x|)))
    float ax = fabsf(x);
    float e  = __expf(-ax);
    float s  = 1.f + e;
    float r  = __builtin_amdgcn_rcpf(s);
    float l1p = __logf(s);
    float ce0 = fmaxf(x, 0.f) + l1p;
    float pr  = (x >= 0.f) ? r : e * r;      // sigmoid(x)
    return 0.75f * pr * pr * ce0;
}

__device__ __forceinline__ float focal_target_corr(float x) {
    // replace t=0 term with t=1 term for the target class
    float ax = fabsf(x);
    float e  = __expf(-ax);
    float s  = 1.f + e;
    float r  = __builtin_amdgcn_rcpf(s);
    float l1p = __logf(s);
    float ce0 = fmaxf(x, 0.f) + l1p;
    float pr  = (x >= 0.f) ? r : e * r;
    float om  = 1.f - pr;
    return 0.25f * om * om * (ce0 - x) - 0.75f * pr * pr * ce0;
}

// byte quantization: coords in [0, ~673] -> /8 grid, values <= 85 < 128
__device__ __forceinline__ int q_rd(float v) { return __float2int_rd(v * 0.125f); }
__device__ __forceinline__ int q_ru(float v) { return __float2int_ru(v * 0.125f); }

__global__ __launch_bounds__(512, 8) void yolo_fused_kernel(
    const float* __restrict__ box_preds,   // [B,N,4]
    const float* __restrict__ cls_preds,   // [B,N,C]
    const float* __restrict__ gt_boxes,    // [B,M,4]
    const int*   __restrict__ gt_labels,   // [B,M]
    float4* __restrict__ partials,         // [nb] per-block {box,cls,npos,-}
    int*    __restrict__ gcnt,             // [ngroups] group done counters, stride 16 ints
    int*    __restrict__ fcnt,             // final done counter
    float*  __restrict__ out,
    int N, int nb)
{
    const int b    = blockIdx.y;
    const int tid  = threadIdx.x;
    const int half = tid >> 8;           // 0: GT[0,64), 1: GT[64,128)
    const int a    = tid & 255;          // anchor slot within block
    const int n    = blockIdx.x * ABLK + a;
    const int lane = tid & 63;
    const int wave = tid >> 6;
    const int bid  = blockIdx.y * gridDim.x + blockIdx.x;

    __shared__ float4   sgt[M_GT];
    __shared__ unsigned spkb[M_GT];      // byte-packed conservative {gx1q,gy1q,127-gx2q,127-gy2q}
    __shared__ int      slbl[M_GT];
    __shared__ float    hbest[ABLK];
    __shared__ int      hidx[ABLK];
    __shared__ int      s_cnt;
    __shared__ bool     s_last;
    __shared__ unsigned plist[ABLK];
    __shared__ float    redb[8], redc[8];

    if (tid == 0) { s_cnt = 0; s_last = false; }
    if (tid < M_GT) {
        float4 g = reinterpret_cast<const float4*>(gt_boxes + (size_t)b * M_GT * 4)[tid];
        sgt[tid]  = g;
        slbl[tid] = gt_labels[b * M_GT + tid];
        unsigned w = (unsigned)q_rd(g.x)
                   | ((unsigned)q_rd(g.y) << 8)
                   | ((unsigned)(127 - q_ru(g.z)) << 16)
                   | ((unsigned)(127 - q_ru(g.w)) << 24);
        spkb[tid] = w;
    }
    __syncthreads();

    const int nld = (n < N) ? n : (N - 1);
    float4 p = reinterpret_cast<const float4*>(box_preds + (size_t)b * N * 4)[nld];
    const float aw = p.z - p.x, ah = p.w - p.y, a1 = aw * ah;

    // anchor word: {px2q_ru, py2q_ru, 127-px1q_rd, 127-py1q_rd}, pre-biased
    const unsigned A = ((unsigned)q_ru(p.z)
                      | ((unsigned)q_ru(p.w) << 8)
                      | ((unsigned)(127 - q_rd(p.x)) << 16)
                      | ((unsigned)(127 - q_rd(p.y)) << 24)) | 0x80808080u;

    // ---- pass 1: conservative overlap mask over this thread's 64-GT half ----
    // per-byte "a >= g": bit7 of (0x80 + a - g); bytes <= 127 -> no cross-byte borrow.
    const uint4* base4 = reinterpret_cast<const uint4*>(spkb) + half * 16;
    unsigned mk[2] = {0u, 0u};
    #pragma unroll 4
    for (int i = 0; i < 16; ++i) {
        uint4 w4 = base4[i];                  // 4 GTs per ds_read_b128 (wave-broadcast)
        unsigned r0 = (A - w4.x) & 0x80808080u;
        unsigned r1 = (A - w4.y) & 0x80808080u;
        unsigned r2 = (A - w4.z) & 0x80808080u;
        unsigned r3 = (A - w4.w) & 0x80808080u;
        unsigned bits = ((r0 == 0x80808080u) ? 1u : 0u)
                      | ((r1 == 0x80808080u) ? 2u : 0u)
                      | ((r2 == 0x80808080u) ? 4u : 0u)
                      | ((r3 == 0x80808080u) ? 8u : 0u);
        mk[i >> 3] |= bits << ((i & 7) * 4);
    }

    // ---- pass 2: exact fp32 GIoU over candidates (ascending -> first-max kept) ----
    float best = -1e30f;   // tracks gip = giou + 1
    int   bidx = half << 6;
    #pragma unroll
    for (int wsel = 0; wsel < 2; ++wsel) {
        unsigned mm = mk[wsel];
        while (mm) {
            int t = __ffs(mm) - 1;
            mm &= mm - 1;
            int m = (half << 6) + (wsel << 5) + t;
            float4 g = sgt[m];
            float gw = g.z - g.x, gh = g.w - g.y, gA = gw * gh;
            float dx = fminf(p.z, g.z) - fmaxf(p.x, g.x);
            float dy = fminf(p.w, g.w) - fmaxf(p.y, g.y);
            float ex = (aw + gw) - dx;            // enclosure extents (identity)
            float ey = (ah + gh) - dy;
            float inter = fmaxf(dx, 0.f) * fmaxf(dy, 0.f);   // clamp: mask is dilated
            float uni = (a1 + gA) - inter;
            float ae  = ex * ey;
            // giou + 1 = (inter*ae + uni^2)/(uni*ae) — single reciprocal
            float gip = fmaf(uni, uni, inter * ae) * __builtin_amdgcn_rcpf(uni * ae);
            if (gip > best) { best = gip; bidx = m; }   // strict > keeps first idx
        }
    }
    // Exactness: positives (giou>0.3) overlap their argmax GT; mask is a superset of
    // overlaps; dilation-extras have inter=0 -> gip<=1<1.3, cannot displace a match.

    // ---- merge GT halves (upper half publishes, lower half merges) ----
    if (half) { hbest[a] = best; hidx[a] = bidx; }
    __syncthreads();
    if (!half) {
        float hb = hbest[a];
        if (hb > best) { best = hb; bidx = hidx[a]; }   // ties keep lower index
    }

    bool  pos   = (!half) && (n < N) && (best > 1.3f);  // giou > 0.3
    float box_l = pos ? (2.f - best) : 0.f;             // 1 - giou

    // ---- block-level compaction of positives (waves 0-3 only can be pos) ----
    {
        unsigned long long mkb = __ballot(pos);
        int cw = __popcll(mkb);
        if (cw > 0) {
            int leader = __ffsll(mkb) - 1;
            int base = 0;
            if (lane == leader) base = atomicAdd(&s_cnt, cw);   // LDS atomic
            base = __shfl(base, leader);
            if (pos) {
                int pre = __popcll(mkb & ((1ull << lane) - 1ull));
                plist[base + pre] = ((unsigned)slbl[bidx] << 18) | (unsigned)(b * N + n);
            }
        }
    }
    __syncthreads();

    // ---- focal: WAVE-cooperative — one positive per wave, lanes split classes ----
    const int cnt = s_cnt;
    float cls_l = 0.f;
    for (int i = wave; i < cnt; i += 8) {
        unsigned u = plist[i];                 // wave-uniform broadcast LDS read
        int row = (int)(u & 0x3FFFFu);
        int lbl = (int)(u >> 18);
        const float* xrow = cls_preds + (size_t)row * NUM_CLASSES;
        float x0 = xrow[lane];
        cls_l += focal_neg(x0);
        if (lane == lbl) cls_l += focal_target_corr(x0);
        if (lane < NUM_CLASSES - 64) {
            float x1 = xrow[64 + lane];
            cls_l += focal_neg(x1);
            if (64 + lane == lbl) cls_l += focal_target_corr(x1);
        }
    }

    // ---- block reduction, publish one partial, two-level done counters ----
    #pragma unroll
    for (int off = 32; off > 0; off >>= 1) {
        box_l += __shfl_down(box_l, off);
        cls_l += __shfl_down(cls_l, off);
    }
    if (lane == 0) { redb[wave] = box_l; redc[wave] = cls_l; }
    __syncthreads();
    if (tid == 0) {
        float b0 = 0.f, c0 = 0.f;
        #pragma unroll
        for (int w = 0; w < 8; ++w) { b0 += redb[w]; c0 += redc[w]; }
        float* slot = (float*)&partials[bid];
        __hip_atomic_store(slot + 0, b0, __ATOMIC_RELAXED, __HIP_MEMORY_SCOPE_AGENT);
        __hip_atomic_store(slot + 1, c0, __ATOMIC_RELAXED, __HIP_MEMORY_SCOPE_AGENT);
        __hip_atomic_store(slot + 2, (float)cnt, __ATOMIC_RELAXED, __HIP_MEMORY_SCOPE_AGENT);
        // two-level completion: ~GRP RMWs per group line, then <=ngroups on final line
        const int gid = bid / GRP;
        const int gtarget = min(GRP, nb - gid * GRP);
        const int ngroups = (nb + GRP - 1) / GRP;
        int gold = __hip_atomic_fetch_add(&gcnt[gid * 16], 1, __ATOMIC_ACQ_REL,
                                          __HIP_MEMORY_SCOPE_AGENT);
        if (gold == gtarget - 1) {
            int fold = __hip_atomic_fetch_add(fcnt, 1, __ATOMIC_ACQ_REL,
                                              __HIP_MEMORY_SCOPE_AGENT);
            s_last = (fold == ngroups - 1);
        }
    }
    __syncthreads();

    // ---- last block: final reduce over all partials ----
    if (s_last) {
        const float* basep = (const float*)partials;
        double sb = 0.0, sc = 0.0, sp = 0.0;
        for (int i = tid; i < nb; i += 512) {
            sb += (double)__hip_atomic_load(basep + 4 * i + 0, __ATOMIC_RELAXED,
                                            __HIP_MEMORY_SCOPE_AGENT);
            sc += (double)__hip_atomic_load(basep + 4 * i + 1, __ATOMIC_RELAXED,
                                            __HIP_MEMORY_SCOPE_AGENT);
            sp += (double)__hip_atomic_load(basep + 4 * i + 2, __ATOMIC_RELAXED,
                                            __HIP_MEMORY_SCOPE_AGENT);
        }
        #pragma unroll
        for (int off = 32; off > 0; off >>= 1) {
            sb += __shfl_down(sb, off);
            sc += __shfl_down(sc, off);
            sp += __shfl_down(sp, off);
        }
        __shared__ double rb[8], rc[8], rp[8];
        if (lane == 0) { rb[wave] = sb; rc[wave] = sc; rp[wave] = sp; }
        __syncthreads();
        if (tid == 0) {
            double B0 = 0.0, C0 = 0.0, P0 = 0.0;
            #pragma unroll
            for (int w = 0; w < 8; ++w) { B0 += rb[w]; C0 += rc[w]; P0 += rp[w]; }
            out[0] = (float)((5.0 * B0 + C0) / fmax(P0, 1.0));
        }
    }
}

extern "C" void kernel_launch(void* const* d_in, const int* in_sizes, int n_in,
                              void* d_out, int out_size, void* d_ws, size_t ws_size,
                              hipStream_t stream) {
    const float* box_preds = (const float*)d_in[0];
    const float* cls_preds = (const float*)d_in[1];
    const float* gt_boxes  = (const float*)d_in[2];
    const int*   gt_labels = (const int*)d_in[3];

    const int B = in_sizes[3] / M_GT;            // gt_labels is [B,M]
    const int N = in_sizes[0] / (4 * B);         // box_preds is [B,N,4]

    // ws layout: [0,2048) group counters (stride 64B), [2048,2052) final counter,
    //            [4096, ...) partials
    int*    gcnt     = (int*)d_ws;
    int*    fcnt     = (int*)((char*)d_ws + 2048);
    float4* partials = (float4*)((char*)d_ws + 4096);
    float*  out      = (float*)d_out;

    const int gx = (N + ABLK - 1) / ABLK;
    const int nb = gx * B;

    (void)hipMemsetAsync(d_ws, 0, 4096, stream);   // zero all counters (graph-safe node)

    dim3 grid(gx, B);
    yolo_fused_kernel<<<grid, 512, 0, stream>>>(box_preds, cls_preds, gt_boxes,
                                                gt_labels, partials, gcnt, fcnt,
                                                out, N, nb);
}

// Round 16
// 29.676 us; speedup vs baseline: 1.3166x; 1.3166x over previous
//
#include <hip/hip_runtime.h>
#include <math.h>

#define NUM_CLASSES 80
#define M_GT 128
#define ABLK 256   // anchors per block == threads per block

__device__ __forceinline__ float focal_neg(float x) {
    // (1-ALPHA)=0.75, t=0 term: 0.75 * p^2 * (max(x,0)+log1p(exp(-|x|)))
    float ax = fabsf(x);
    float e  = __expf(-ax);
    float s  = 1.f + e;
    float r  = __builtin_amdgcn_rcpf(s);
    float l1p = __logf(s);
    float ce0 = fmaxf(x, 0.f) + l1p;
    float pr  = (x >= 0.f) ? r : e * r;      // sigmoid(x)
    return 0.75f * pr * pr * ce0;
}

__device__ __forceinline__ float focal_target_corr(float x) {
    // replace t=0 term with t=1 term for the target class
    float ax = fabsf(x);
    float e  = __expf(-ax);
    float s  = 1.f + e;
    float r  = __builtin_amdgcn_rcpf(s);
    float l1p = __logf(s);
    float ce0 = fmaxf(x, 0.f) + l1p;
    float pr  = (x >= 0.f) ? r : e * r;
    float om  = 1.f - pr;
    return 0.25f * om * om * (ce0 - x) - 0.75f * pr * pr * ce0;
}

// byte quantization: coords in [0, ~673] -> /8 grid, values <= 85 < 128
__device__ __forceinline__ int q_rd(float v) { return __float2int_rd(v * 0.125f); }
__device__ __forceinline__ int q_ru(float v) { return __float2int_ru(v * 0.125f); }

__global__ __launch_bounds__(256, 8) void yolo_fused_kernel(
    const float* __restrict__ box_preds,   // [B,N,4]
    const float* __restrict__ cls_preds,   // [B,N,C]
    const float* __restrict__ gt_boxes,    // [B,M,4]
    const int*   __restrict__ gt_labels,   // [B,M]
    float4* __restrict__ partials,         // [nb] per-block {box,cls,npos,-}
    int N)
{
    const int b    = blockIdx.y;
    const int tid  = threadIdx.x;
    const int n    = blockIdx.x * ABLK + tid;
    const int lane = tid & 63;
    const int wave = tid >> 6;

    __shared__ float4   sgt[M_GT];
    __shared__ unsigned spkb[M_GT];      // byte-packed conservative {gx1q,gy1q,127-gx2q,127-gy2q}
    __shared__ int      slbl[M_GT];
    __shared__ int      s_cnt;
    __shared__ unsigned plist[ABLK];
    __shared__ float    redb[4], redc[4];

    if (tid == 0) s_cnt = 0;
    if (tid < M_GT) {
        float4 g = reinterpret_cast<const float4*>(gt_boxes + (size_t)b * M_GT * 4)[tid];
        sgt[tid]  = g;
        slbl[tid] = gt_labels[b * M_GT + tid];
        unsigned w = (unsigned)q_rd(g.x)
                   | ((unsigned)q_rd(g.y) << 8)
                   | ((unsigned)(127 - q_ru(g.z)) << 16)
                   | ((unsigned)(127 - q_ru(g.w)) << 24);
        spkb[tid] = w;
    }
    __syncthreads();

    const int nld = (n < N) ? n : (N - 1);
    float4 p = reinterpret_cast<const float4*>(box_preds + (size_t)b * N * 4)[nld];
    const float aw = p.z - p.x, ah = p.w - p.y, a1 = aw * ah;

    // anchor word: {px2q_ru, py2q_ru, 127-px1q_rd, 127-py1q_rd}, pre-biased
    const unsigned A = ((unsigned)q_ru(p.z)
                      | ((unsigned)q_ru(p.w) << 8)
                      | ((unsigned)(127 - q_rd(p.x)) << 16)
                      | ((unsigned)(127 - q_rd(p.y)) << 24)) | 0x80808080u;

    // ---- pass 1: conservative overlap mask over all 128 GTs ----
    // per-byte "a >= g": bit7 of (0x80 + a - g); bytes <= 127 -> no cross-byte borrow.
    const uint4* base4 = reinterpret_cast<const uint4*>(spkb);
    unsigned mk[4] = {0u, 0u, 0u, 0u};
    #pragma unroll 4
    for (int i = 0; i < 32; ++i) {
        uint4 w4 = base4[i];                  // 4 GTs per ds_read_b128 (wave-broadcast)
        unsigned r0 = (A - w4.x) & 0x80808080u;
        unsigned r1 = (A - w4.y) & 0x80808080u;
        unsigned r2 = (A - w4.z) & 0x80808080u;
        unsigned r3 = (A - w4.w) & 0x80808080u;
        unsigned bits = ((r0 == 0x80808080u) ? 1u : 0u)
                      | ((r1 == 0x80808080u) ? 2u : 0u)
                      | ((r2 == 0x80808080u) ? 4u : 0u)
                      | ((r3 == 0x80808080u) ? 8u : 0u);
        mk[i >> 3] |= bits << ((i & 7) * 4);
    }

    // ---- pass 2: exact fp32 GIoU over candidates (ascending -> first-max kept) ----
    float best = -1e30f;   // tracks gip = giou + 1
    int   bidx = 0;
    #pragma unroll
    for (int wsel = 0; wsel < 4; ++wsel) {
        unsigned mm = mk[wsel];
        while (mm) {
            int t = __ffs(mm) - 1;
            mm &= mm - 1;
            int m = (wsel << 5) + t;
            float4 g = sgt[m];
            float gw = g.z - g.x, gh = g.w - g.y, gA = gw * gh;
            float dx = fminf(p.z, g.z) - fmaxf(p.x, g.x);
            float dy = fminf(p.w, g.w) - fmaxf(p.y, g.y);
            float ex = (aw + gw) - dx;            // enclosure extents (identity)
            float ey = (ah + gh) - dy;
            float inter = fmaxf(dx, 0.f) * fmaxf(dy, 0.f);   // clamp: mask is dilated
            float uni = (a1 + gA) - inter;
            float ae  = ex * ey;
            // giou + 1 = (inter*ae + uni^2)/(uni*ae) — single reciprocal
            float gip = fmaf(uni, uni, inter * ae) * __builtin_amdgcn_rcpf(uni * ae);
            if (gip > best) { best = gip; bidx = m; }   // strict > keeps first idx
        }
    }
    // Exactness: positives (giou>0.3) overlap their argmax GT; mask is a superset of
    // overlaps; dilation-extras have inter=0 -> gip<=1<1.3, cannot displace a match.

    bool  pos   = (n < N) && (best > 1.3f);     // giou > 0.3
    float box_l = pos ? (2.f - best) : 0.f;     // 1 - giou (elementwise giou == best)

    // ---- block-level compaction of positives ----
    {
        unsigned long long mkb = __ballot(pos);
        int cw = __popcll(mkb);
        if (cw > 0) {
            int leader = __ffsll(mkb) - 1;
            int base = 0;
            if (lane == leader) base = atomicAdd(&s_cnt, cw);   // LDS atomic
            base = __shfl(base, leader);
            if (pos) {
                int pre = __popcll(mkb & ((1ull << lane) - 1ull));
                plist[base + pre] = ((unsigned)slbl[bidx] << 18) | (unsigned)(b * N + n);
            }
        }
    }
    __syncthreads();

    // ---- focal: WAVE-cooperative — one positive per wave, lanes split classes ----
    const int cnt = s_cnt;
    float cls_l = 0.f;
    for (int i = wave; i < cnt; i += 4) {
        unsigned u = plist[i];                 // wave-uniform broadcast LDS read
        int row = (int)(u & 0x3FFFFu);
        int lbl = (int)(u >> 18);
        const float* xrow = cls_preds + (size_t)row * NUM_CLASSES;
        float x0 = xrow[lane];
        cls_l += focal_neg(x0);
        if (lane == lbl) cls_l += focal_target_corr(x0);
        if (lane < NUM_CLASSES - 64) {
            float x1 = xrow[64 + lane];
            cls_l += focal_neg(x1);
            if (64 + lane == lbl) cls_l += focal_target_corr(x1);
        }
    }

    // ---- block reduction, then ONE plain store per block (no global atomics) ----
    #pragma unroll
    for (int off = 32; off > 0; off >>= 1) {
        box_l += __shfl_down(box_l, off);
        cls_l += __shfl_down(cls_l, off);
    }
    if (lane == 0) { redb[wave] = box_l; redc[wave] = cls_l; }
    __syncthreads();
    if (tid == 0) {
        float b0 = redb[0] + redb[1] + redb[2] + redb[3];
        float c0 = redc[0] + redc[1] + redc[2] + redc[3];
        partials[blockIdx.y * gridDim.x + blockIdx.x] = make_float4(b0, c0, (float)cnt, 0.f);
    }
}

__global__ __launch_bounds__(256) void yolo_reduce(const float4* __restrict__ partials,
                                                   int nb, float* __restrict__ out) {
    const int tid = threadIdx.x;
    const int lane = tid & 63, wave = tid >> 6;
    double sb = 0.0, sc = 0.0, sp = 0.0;
    for (int i = tid; i < nb; i += 256) {
        float4 v = partials[i];
        sb += (double)v.x; sc += (double)v.y; sp += (double)v.z;
    }
    #pragma unroll
    for (int off = 32; off > 0; off >>= 1) {
        sb += __shfl_down(sb, off);
        sc += __shfl_down(sc, off);
        sp += __shfl_down(sp, off);
    }
    __shared__ double rb[4], rc[4], rp[4];
    if (lane == 0) { rb[wave] = sb; rc[wave] = sc; rp[wave] = sp; }
    __syncthreads();
    if (tid == 0) {
        double B0 = rb[0] + rb[1] + rb[2] + rb[3];
        double C0 = rc[0] + rc[1] + rc[2] + rc[3];
        double P0 = rp[0] + rp[1] + rp[2] + rp[3];
        out[0] = (float)((5.0 * B0 + C0) / fmax(P0, 1.0));
    }
}

extern "C" void kernel_launch(void* const* d_in, const int* in_sizes, int n_in,
                              void* d_out, int out_size, void* d_ws, size_t ws_size,
                              hipStream_t stream) {
    const float* box_preds = (const float*)d_in[0];
    const float* cls_preds = (const float*)d_in[1];
    const float* gt_boxes  = (const float*)d_in[2];
    const int*   gt_labels = (const int*)d_in[3];

    const int B = in_sizes[3] / M_GT;            // gt_labels is [B,M]
    const int N = in_sizes[0] / (4 * B);         // box_preds is [B,N,4]

    float4* partials = (float4*)d_ws;
    float*  out      = (float*)d_out;

    const int gx = (N + ABLK - 1) / ABLK;
    dim3 grid(gx, B);
    yolo_fused_kernel<<<grid, 256, 0, stream>>>(box_preds, cls_preds, gt_boxes,
                                                gt_labels, partials, N);

    yolo_reduce<<<1, 256, 0, stream>>>(partials, gx * B, out);
}

// Round 17
// 26.074 us; speedup vs baseline: 1.4985x; 1.1381x over previous
//
#include <hip/hip_runtime.h>
#include <math.h>

#define NUM_CLASSES 80
#define M_GT 128
#define ABLK 256   // anchors per block; 512 threads = 2 GT-halves per anchor

__device__ __forceinline__ float focal_neg(float x) {
    // (1-ALPHA)=0.75, t=0 term: 0.75 * p^2 * (max(x,0)+log1p(exp(-|x|)))
    float ax = fabsf(x);
    float e  = __expf(-ax);
    float s  = 1.f + e;
    float r  = __builtin_amdgcn_rcpf(s);
    float l1p = __logf(s);
    float ce0 = fmaxf(x, 0.f) + l1p;
    float pr  = (x >= 0.f) ? r : e * r;      // sigmoid(x)
    return 0.75f * pr * pr * ce0;
}

__device__ __forceinline__ float focal_target_corr(float x) {
    // replace t=0 term with t=1 term for the target class
    float ax = fabsf(x);
    float e  = __expf(-ax);
    float s  = 1.f + e;
    float r  = __builtin_amdgcn_rcpf(s);
    float l1p = __logf(s);
    float ce0 = fmaxf(x, 0.f) + l1p;
    float pr  = (x >= 0.f) ? r : e * r;
    float om  = 1.f - pr;
    return 0.25f * om * om * (ce0 - x) - 0.75f * pr * pr * ce0;
}

// byte quantization: coords in [0, ~673] -> /8 grid, values <= 85 < 128
__device__ __forceinline__ int q_rd(float v) { return __float2int_rd(v * 0.125f); }
__device__ __forceinline__ int q_ru(float v) { return __float2int_ru(v * 0.125f); }

__global__ __launch_bounds__(512, 8) void yolo_fused_kernel(
    const float* __restrict__ box_preds,   // [B,N,4]
    const float* __restrict__ cls_preds,   // [B,N,C]
    const float* __restrict__ gt_boxes,    // [B,M,4]
    const int*   __restrict__ gt_labels,   // [B,M]
    float4* __restrict__ partials,         // [nb] per-block {box,cls,npos,-}
    int N)
{
    const int b    = blockIdx.y;
    const int tid  = threadIdx.x;
    const int half = tid >> 8;           // 0: GT[0,64), 1: GT[64,128)
    const int a    = tid & 255;          // anchor slot within block
    const int n    = blockIdx.x * ABLK + a;
    const int lane = tid & 63;
    const int wave = tid >> 6;

    __shared__ float4   sgt[M_GT];
    __shared__ unsigned spkb[M_GT];      // byte-packed conservative {gx1q,gy1q,127-gx2q,127-gy2q}
    __shared__ int      slbl[M_GT];
    __shared__ float    hbest[ABLK];
    __shared__ int      hidx[ABLK];
    __shared__ int      s_cnt;
    __shared__ unsigned plist[ABLK];
    __shared__ float    redb[8], redc[8];

    // issue the anchor load FIRST: its latency overlaps GT staging + barrier drain
    const int nld = (n < N) ? n : (N - 1);
    float4 p = reinterpret_cast<const float4*>(box_preds + (size_t)b * N * 4)[nld];

    if (tid == 0) s_cnt = 0;
    if (tid < M_GT) {
        float4 g = reinterpret_cast<const float4*>(gt_boxes + (size_t)b * M_GT * 4)[tid];
        sgt[tid]  = g;
        slbl[tid] = gt_labels[b * M_GT + tid];
        unsigned w = (unsigned)q_rd(g.x)
                   | ((unsigned)q_rd(g.y) << 8)
                   | ((unsigned)(127 - q_ru(g.z)) << 16)
                   | ((unsigned)(127 - q_ru(g.w)) << 24);
        spkb[tid] = w;
    }
    __syncthreads();

    const float aw = p.z - p.x, ah = p.w - p.y, a1 = aw * ah;

    // anchor word: {px2q_ru, py2q_ru, 127-px1q_rd, 127-py1q_rd}, pre-biased
    const unsigned A = ((unsigned)q_ru(p.z)
                      | ((unsigned)q_ru(p.w) << 8)
                      | ((unsigned)(127 - q_rd(p.x)) << 16)
                      | ((unsigned)(127 - q_rd(p.y)) << 24)) | 0x80808080u;

    // ---- pass 1: conservative overlap mask over this thread's 64-GT half ----
    // per-byte "a >= g": bit7 of (0x80 + a - g); bytes <= 127 -> no cross-byte borrow.
    const uint4* base4 = reinterpret_cast<const uint4*>(spkb) + half * 16;
    unsigned mk[2] = {0u, 0u};
    #pragma unroll 4
    for (int i = 0; i < 16; ++i) {
        uint4 w4 = base4[i];                  // 4 GTs per ds_read_b128 (wave-broadcast)
        unsigned r0 = (A - w4.x) & 0x80808080u;
        unsigned r1 = (A - w4.y) & 0x80808080u;
        unsigned r2 = (A - w4.z) & 0x80808080u;
        unsigned r3 = (A - w4.w) & 0x80808080u;
        unsigned bits = ((r0 == 0x80808080u) ? 1u : 0u)
                      | ((r1 == 0x80808080u) ? 2u : 0u)
                      | ((r2 == 0x80808080u) ? 4u : 0u)
                      | ((r3 == 0x80808080u) ? 8u : 0u);
        mk[i >> 3] |= bits << ((i & 7) * 4);
    }

    // ---- pass 2: exact fp32 GIoU over candidates (ascending -> first-max kept) ----
    float best = -1e30f;   // tracks gip = giou + 1
    int   bidx = half << 6;
    #pragma unroll
    for (int wsel = 0; wsel < 2; ++wsel) {
        unsigned mm = mk[wsel];
        while (mm) {
            int t = __ffs(mm) - 1;
            mm &= mm - 1;
            int m = (half << 6) + (wsel << 5) + t;
            float4 g = sgt[m];
            float gw = g.z - g.x, gh = g.w - g.y, gA = gw * gh;
            float dx = fminf(p.z, g.z) - fmaxf(p.x, g.x);
            float dy = fminf(p.w, g.w) - fmaxf(p.y, g.y);
            float ex = (aw + gw) - dx;            // enclosure extents (identity)
            float ey = (ah + gh) - dy;
            float inter = fmaxf(dx, 0.f) * fmaxf(dy, 0.f);   // clamp: mask is dilated
            float uni = (a1 + gA) - inter;
            float ae  = ex * ey;
            // giou + 1 = (inter*ae + uni^2)/(uni*ae) — single reciprocal
            float gip = fmaf(uni, uni, inter * ae) * __builtin_amdgcn_rcpf(uni * ae);
            if (gip > best) { best = gip; bidx = m; }   // strict > keeps first idx
        }
    }
    // Exactness: positives (giou>0.3) overlap their argmax GT; mask is a superset of
    // overlaps; dilation-extras have inter=0 -> gip<=1<1.3, cannot displace a match.

    // ---- merge GT halves (upper half publishes, lower half merges) ----
    if (half) { hbest[a] = best; hidx[a] = bidx; }
    __syncthreads();
    if (!half) {
        float hb = hbest[a];
        if (hb > best) { best = hb; bidx = hidx[a]; }   // ties keep lower index
    }

    bool  pos   = (!half) && (n < N) && (best > 1.3f);  // giou > 0.3
    float box_l = pos ? (2.f - best) : 0.f;             // 1 - giou

    // ---- block-level compaction of positives (waves 0-3 only can be pos) ----
    {
        unsigned long long mkb = __ballot(pos);
        int cw = __popcll(mkb);
        if (cw > 0) {
            int leader = __ffsll(mkb) - 1;
            int base = 0;
            if (lane == leader) base = atomicAdd(&s_cnt, cw);   // LDS atomic
            base = __shfl(base, leader);
            if (pos) {
                int pre = __popcll(mkb & ((1ull << lane) - 1ull));
                plist[base + pre] = ((unsigned)slbl[bidx] << 18) | (unsigned)(b * N + n);
            }
        }
    }
    __syncthreads();

    // ---- focal: WAVE-cooperative — one positive per wave, lanes split classes ----
    const int cnt = s_cnt;
    float cls_l = 0.f;
    for (int i = wave; i < cnt; i += 8) {
        unsigned u = plist[i];                 // wave-uniform broadcast LDS read
        int row = (int)(u & 0x3FFFFu);
        int lbl = (int)(u >> 18);
        const float* xrow = cls_preds + (size_t)row * NUM_CLASSES;
        float x0 = xrow[lane];
        cls_l += focal_neg(x0);
        if (lane == lbl) cls_l += focal_target_corr(x0);
        if (lane < NUM_CLASSES - 64) {
            float x1 = xrow[64 + lane];
            cls_l += focal_neg(x1);
            if (64 + lane == lbl) cls_l += focal_target_corr(x1);
        }
    }

    // ---- block reduction, then ONE plain store per block (no global atomics) ----
    #pragma unroll
    for (int off = 32; off > 0; off >>= 1) {
        box_l += __shfl_down(box_l, off);
        cls_l += __shfl_down(cls_l, off);
    }
    if (lane == 0) { redb[wave] = box_l; redc[wave] = cls_l; }
    __syncthreads();
    if (tid == 0) {
        float b0 = 0.f, c0 = 0.f;
        #pragma unroll
        for (int w = 0; w < 8; ++w) { b0 += redb[w]; c0 += redc[w]; }
        partials[blockIdx.y * gridDim.x + blockIdx.x] = make_float4(b0, c0, (float)s_cnt, 0.f);
    }
}

__global__ __launch_bounds__(256) void yolo_reduce(const float4* __restrict__ partials,
                                                   int nb, float* __restrict__ out) {
    const int tid = threadIdx.x;
    const int lane = tid & 63, wave = tid >> 6;
    double sb = 0.0, sc = 0.0, sp = 0.0;
    for (int i = tid; i < nb; i += 256) {
        float4 v = partials[i];
        sb += (double)v.x; sc += (double)v.y; sp += (double)v.z;
    }
    #pragma unroll
    for (int off = 32; off > 0; off >>= 1) {
        sb += __shfl_down(sb, off);
        sc += __shfl_down(sc, off);
        sp += __shfl_down(sp, off);
    }
    __shared__ double rb[4], rc[4], rp[4];
    if (lane == 0) { rb[wave] = sb; rc[wave] = sc; rp[wave] = sp; }
    __syncthreads();
    if (tid == 0) {
        double B0 = rb[0] + rb[1] + rb[2] + rb[3];
        double C0 = rc[0] + rc[1] + rc[2] + rc[3];
        double P0 = rp[0] + rp[1] + rp[2] + rp[3];
        out[0] = (float)((5.0 * B0 + C0) / fmax(P0, 1.0));
    }
}

extern "C" void kernel_launch(void* const* d_in, const int* in_sizes, int n_in,
                              void* d_out, int out_size, void* d_ws, size_t ws_size,
                              hipStream_t stream) {
    const float* box_preds = (const float*)d_in[0];
    const float* cls_preds = (const float*)d_in[1];
    const float* gt_boxes  = (const float*)d_in[2];
    const int*   gt_labels = (const int*)d_in[3];

    const int B = in_sizes[3] / M_GT;            // gt_labels is [B,M]
    const int N = in_sizes[0] / (4 * B);         // box_preds is [B,N,4]

    float4* partials = (float4*)d_ws;
    float*  out      = (float*)d_out;

    const int gx = (N + ABLK - 1) / ABLK;
    dim3 grid(gx, B);
    yolo_fused_kernel<<<grid, 512, 0, stream>>>(box_preds, cls_preds, gt_boxes,
                                                gt_labels, partials, N);

    yolo_reduce<<<1, 256, 0, stream>>>(partials, gx * B, out);
}